// Round 7
// baseline (387.556 us; speedup 1.0000x reference)
//
#include <hip/hip_runtime.h>
#include <hip/hip_bf16.h>

#define BN 8
#define LN 4096
#define HN 2048
#define EN 512
#define KN 64
#define LT 32
#define NIT 128

typedef __attribute__((ext_vector_type(8))) short bf16x8;
typedef __attribute__((ext_vector_type(4))) float f32x4;
typedef __attribute__((ext_vector_type(4))) unsigned u32x4;

__device__ __forceinline__ short f2b(float x) {
  union { float f; unsigned u; } v; v.f = x;
  unsigned r = v.u + 0x7fffu + ((v.u >> 16) & 1u);  // RNE f32->bf16
  return (short)(r >> 16);
}

__device__ __forceinline__ bf16x8 cvt8s(const float* __restrict__ p, float s) {
  f32x4 a = *(const f32x4*)(p);
  f32x4 b = *(const f32x4*)(p + 4);
  bf16x8 r;
  r[0] = f2b(a[0] * s); r[1] = f2b(a[1] * s); r[2] = f2b(a[2] * s); r[3] = f2b(a[3] * s);
  r[4] = f2b(b[0] * s); r[5] = f2b(b[1] * s); r[6] = f2b(b[2] * s); r[7] = f2b(b[3] * s);
  return r;
}

__device__ __forceinline__ void gload16(const void* g, void* s) {
  __builtin_amdgcn_global_load_lds(
      (const __attribute__((address_space(1))) unsigned int*)(unsigned long long)g,
      (__attribute__((address_space(3))) unsigned int*)(unsigned int)(unsigned long long)s,
      16, 0, 0);
}

// ---------- merged prep: cvt (0..1535) | prep_v (1536..5631) | stats raw (5632..6655) ----------
__global__ __launch_bounds__(256) void k_prep(const float* __restrict__ vals,
                                              short* __restrict__ valsT,
                                              const float* __restrict__ xd,
                                              short* __restrict__ xo,
                                              const float* __restrict__ yd,
                                              short* __restrict__ yo,
                                              float* __restrict__ ps) {
  __shared__ unsigned trT[2048];
  const int bx = blockIdx.x;
  const int tid = threadIdx.x;
  const float c0 = 0.125f * 1.4426950408889634f;  // scale * log2(e)
  if (bx < 1536) {
    // ---- cvt: x scaled (bx<1024), y (1024..1535) ----
    const float* src;
    short* dst;
    float scale;
    int i;
    if (bx < 1024) { i = bx * 256 + tid; src = xd; dst = xo; scale = c0; }
    else           { i = (bx - 1024) * 256 + tid; src = yd; dst = yo; scale = 1.0f; }
    *(bf16x8*)(dst + (size_t)i * 8) = cvt8s(src + (size_t)i * 8, scale);
  } else if (bx < 5632) {
    // ---- prep_v: vals [b][l][e] f32 -> valsT [b][e][l] bf16 (64x64 tile) ----
    const int idx = bx - 1536;
    const int b = idx >> 9;
    const int e0 = ((idx >> 6) & 7) * 64;
    const int l0 = (idx & 63) * 64;
    {
      int lr2 = tid >> 3;
      int ec = (tid & 7) * 8;
      const float* r0 = vals + ((size_t)b * LN + l0 + 2 * lr2) * EN + e0 + ec;
      const float* r1 = r0 + EN;
      f32x4 a0 = *(const f32x4*)r0, a1 = *(const f32x4*)(r0 + 4);
      f32x4 cc0 = *(const f32x4*)r1, cc1 = *(const f32x4*)(r1 + 4);
#pragma unroll
      for (int j = 0; j < 8; ++j) {
        float lo = (j < 4) ? a0[j] : a1[j - 4];
        float hi = (j < 4) ? cc0[j] : cc1[j - 4];
        unsigned dw = (unsigned)(unsigned short)f2b(lo) |
                      ((unsigned)(unsigned short)f2b(hi) << 16);
        int e = ec + j;
        int sz = (((e >> 3) ^ e) & 7) << 2;
        trT[e * 32 + (lr2 ^ sz)] = dw;
      }
    }
    __syncthreads();
    {
      int er = tid >> 2, lq = (tid & 3) * 8;
      int sr = ((er >> 3) ^ er) & 7;
      const unsigned* base = trT + er * 32;
      u32x4 u0 = *(const u32x4*)(base + ((((lq >> 2) + 0) ^ sr) << 2));
      u32x4 u1 = *(const u32x4*)(base + ((((lq >> 2) + 1) ^ sr) << 2));
      short* dst = valsT + ((size_t)b * EN + e0 + er) * LN + l0 + 2 * lq;
      *(u32x4*)dst = u0;
      *(u32x4*)(dst + 8) = u1;
    }
  } else {
    // ---- stats (raw f32 in, identical f2b rounding): ps[hc][b][l] = sum_512h 2^u ----
    const int idx = bx - 5632;
    const int b = (idx >> 5) & 7, hc = idx >> 8;
    const int w = tid >> 6, lane = tid & 63;
    const int row = lane & 15, g = lane >> 4;
    const int lb = (idx & 31) * 128 + w * 32;
    const size_t bL = (size_t)b * LN, bH = (size_t)b * HN;
    bf16x8 xa[2][2];
#pragma unroll
    for (int lt = 0; lt < 2; ++lt) {
      const float* xp = xd + (bL + lb + lt * 16 + row) * KN + g * 8;
      xa[lt][0] = cvt8s(xp, c0);
      xa[lt][1] = cvt8s(xp + 32, c0);
    }
    float s[2][4] = {{0.f, 0.f, 0.f, 0.f}, {0.f, 0.f, 0.f, 0.f}};
    const float* ybase = yd + (bH + hc * 512 + row) * KN + g * 8;
#pragma unroll 2
    for (int it = 0; it < 32; ++it) {
      const float* yp = ybase + (size_t)it * (16 * KN);
      bf16x8 y0 = cvt8s(yp, 1.0f);
      bf16x8 y1 = cvt8s(yp + 32, 1.0f);
#pragma unroll
      for (int lt = 0; lt < 2; ++lt) {
        f32x4 a = {0.f, 0.f, 0.f, 0.f};
        a = __builtin_amdgcn_mfma_f32_16x16x32_bf16(xa[lt][0], y0, a, 0, 0, 0);
        a = __builtin_amdgcn_mfma_f32_16x16x32_bf16(xa[lt][1], y1, a, 0, 0, 0);
#pragma unroll
        for (int r = 0; r < 4; ++r) s[lt][r] += __builtin_amdgcn_exp2f(a[r]);
      }
    }
#pragma unroll
    for (int d = 1; d < 16; d <<= 1)
#pragma unroll
      for (int lt = 0; lt < 2; ++lt)
#pragma unroll
        for (int r = 0; r < 4; ++r) s[lt][r] += __shfl_xor(s[lt][r], d);
    if (row == 0) {
#pragma unroll
      for (int lt = 0; lt < 2; ++lt)
#pragma unroll
        for (int r = 0; r < 4; ++r)
          ps[(size_t)hc * (BN * LN) + bL + lb + lt * 16 + 4 * g + r] = s[lt][r];
    }
  }
}

__global__ void k_comb(const float* __restrict__ ps, float* __restrict__ wv) {
  int idx = blockIdx.x * 256 + threadIdx.x;
  float z = ps[idx] + ps[BN * LN + idx] + ps[2 * BN * LN + idx] + ps[3 * BN * LN + idx];
  wv[idx] = 1.0f / z;
}

// ---------- main v6: V direct global->VGPR (L2-hit), LDS only xT+pT (20.5 KB) ----------
// LDS: xT[3]x4096 @0 | pT[2]x4096 @12288
__global__ __launch_bounds__(512, 4) void k_main6(
    const short* __restrict__ valsT, const short* __restrict__ xb,
    const short* __restrict__ yb, const float* __restrict__ wv,
    float* __restrict__ out) {
  __shared__ __align__(16) char smem[20480];
  const int tid = threadIdx.x;
  const int w = tid >> 6, lane = tid & 63;
  const int row = lane & 15, g = lane >> 4;

  const int f = blockIdx.x;
  const int b = f & 7;                 // XCD f%8 <- batch b (valsT[b] 4MB per XCD L2)
  const int rest = f >> 3;
  const int hb = (rest & 31) * 64;
  const int eb = (rest >> 5) * 256;
  const size_t bL = (size_t)b * LN, bH = (size_t)b * HN;
  const int wbase = __builtin_amdgcn_readfirstlane(tid & ~63);

  // ---- xT staging (lanes<32 of each wave; 4 KB/tile; x rows contiguous) ----
  const short* xsrc;
  {
    int p = w * 32 + (lane & 31);
    int l = p >> 3, sl = (p & 7) ^ (l & 7);
    xsrc = xb + ((bL + l) << 6) + 8 * sl;
  }
  auto stage_x = [&](int t) {
    if (lane < 32)
      gload16(xsrc + ((size_t)t << 11), smem + (t % 3) * 4096 + wbase * 8);
  };

  // ---- produce role: wave w -> h-tile ht, l-tile lt ----
  const int ht = w >> 1, lt = w & 1;
  bf16x8 ya0, ya1;
  {
    const short* yp = yb + ((bH + hb + ht * 16 + row) << 6) + 8 * g;
    ya0 = *(const bf16x8*)yp;
    ya1 = *(const bf16x8*)(yp + 32);
  }
  const int sp0 = g ^ (row & 7);
  const int xoffA = ((lt * 16 + row) << 7) + (sp0 << 4);
  const int xoffB = ((lt * 16 + row) << 7) + ((sp0 ^ 4) << 4);
  const int hq1 = ht * 16 + row;
  const int poff_w = hq1 * 64 + (((2 * lt + (g >> 1)) ^ ((hq1 >> 1) & 3)) << 4) + (g & 1) * 8;
  const float* swsrc = wv + bL + lt * 16 + 4 * g;  // + t*32 per tile

  // ---- consume role: wave w -> h-half (w>>2), e-quarter (w&3) ----
  const int hq2a = (w >> 2) * 32 + row, hq2b = hq2a + 16;
  const int paoffA = 12288 + hq2a * 64 + ((g ^ ((hq2a >> 1) & 3)) << 4);
  const int paoffB = 12288 + hq2b * 64 + ((g ^ ((hq2b >> 1) & 3)) << 4);
  const short* vp[4];
#pragma unroll
  for (int n = 0; n < 4; ++n) {
    int el = (w & 3) * 64 + n * 16 + row;
    vp[n] = valsT + ((size_t)b * EN + eb + el) * LN + g * 8;  // 16B frag, advances 32/tile
  }

  f32x4 acc[2][4];
#pragma unroll
  for (int at = 0; at < 2; ++at)
#pragma unroll
    for (int n = 0; n < 4; ++n) acc[at][n] = (f32x4){0.f, 0.f, 0.f, 0.f};

  f32x4 sws_cur, sws_next;

  auto produce = [&](int t, f32x4 sws) {
    const char* xbuf = smem + (t % 3) * 4096;
    bf16x8 xa0 = *(const bf16x8*)(xbuf + xoffA);
    bf16x8 xa1 = *(const bf16x8*)(xbuf + xoffB);
    f32x4 s4 = {0.f, 0.f, 0.f, 0.f};
    s4 = __builtin_amdgcn_mfma_f32_16x16x32_bf16(xa0, ya0, s4, 0, 0, 0);
    s4 = __builtin_amdgcn_mfma_f32_16x16x32_bf16(xa1, ya1, s4, 0, 0, 0);
    unsigned u0 = (unsigned)(unsigned short)f2b(__builtin_amdgcn_exp2f(s4[0]) * sws[0]) |
                  ((unsigned)(unsigned short)f2b(__builtin_amdgcn_exp2f(s4[1]) * sws[1]) << 16);
    unsigned u1 = (unsigned)(unsigned short)f2b(__builtin_amdgcn_exp2f(s4[2]) * sws[2]) |
                  ((unsigned)(unsigned short)f2b(__builtin_amdgcn_exp2f(s4[3]) * sws[3]) << 16);
    *(unsigned long long*)(smem + 12288 + (t & 1) * 4096 + poff_w) =
        (unsigned long long)u0 | ((unsigned long long)u1 << 32);
  };

  // ---- prologue ----
  stage_x(0);
  stage_x(1);
  sws_cur = *(const f32x4*)(swsrc);
  sws_next = *(const f32x4*)(swsrc + 32);
  asm volatile("s_waitcnt vmcnt(0)" ::: "memory");
  __builtin_amdgcn_s_barrier();
  asm volatile("" ::: "memory");
  produce(0, sws_cur);
  sws_cur = sws_next;
  asm volatile("s_waitcnt lgkmcnt(0)" ::: "memory");
  __builtin_amdgcn_s_barrier();
  asm volatile("" ::: "memory");

  for (int it = 0; it < NIT - 1; ++it) {
    const int p = it & 1;
    // pa early (ds_read latency hidden under produce)
    const char* pb = smem + p * 4096;
    bf16x8 pa0 = *(const bf16x8*)(pb + paoffA);
    bf16x8 pa1 = *(const bf16x8*)(pb + paoffB);
    // xT gload pinned oldest among this iter's VMEM
    if (it + 2 < NIT) stage_x(it + 2);
    __builtin_amdgcn_sched_barrier(0);
    // V(it) direct from L2 -> regs
    bf16x8 vb0 = *(const bf16x8*)(vp[0]);
    bf16x8 vb1 = *(const bf16x8*)(vp[1]);
    bf16x8 vb2 = *(const bf16x8*)(vp[2]);
    bf16x8 vb3 = *(const bf16x8*)(vp[3]);
    if (it + 2 < NIT) sws_next = *(const f32x4*)(swsrc + (it + 2) * 32);
    // P(it+1) -> pT[p^1]
    produce(it + 1, sws_cur);
    sws_cur = sws_next;
    // consume(it)
    __builtin_amdgcn_s_setprio(1);
    acc[0][0] = __builtin_amdgcn_mfma_f32_16x16x32_bf16(pa0, vb0, acc[0][0], 0, 0, 0);
    acc[1][0] = __builtin_amdgcn_mfma_f32_16x16x32_bf16(pa1, vb0, acc[1][0], 0, 0, 0);
    acc[0][1] = __builtin_amdgcn_mfma_f32_16x16x32_bf16(pa0, vb1, acc[0][1], 0, 0, 0);
    acc[1][1] = __builtin_amdgcn_mfma_f32_16x16x32_bf16(pa1, vb1, acc[1][1], 0, 0, 0);
    acc[0][2] = __builtin_amdgcn_mfma_f32_16x16x32_bf16(pa0, vb2, acc[0][2], 0, 0, 0);
    acc[1][2] = __builtin_amdgcn_mfma_f32_16x16x32_bf16(pa1, vb2, acc[1][2], 0, 0, 0);
    acc[0][3] = __builtin_amdgcn_mfma_f32_16x16x32_bf16(pa0, vb3, acc[0][3], 0, 0, 0);
    acc[1][3] = __builtin_amdgcn_mfma_f32_16x16x32_bf16(pa1, vb3, acc[1][3], 0, 0, 0);
    __builtin_amdgcn_s_setprio(0);
    vp[0] += 32; vp[1] += 32; vp[2] += 32; vp[3] += 32;
    // xT drained (it is older than the V loads the MFMAs just waited on);
    // vmcnt(1) allows sws_next to stay in flight.
    asm volatile("s_waitcnt vmcnt(1) lgkmcnt(0)" ::: "memory");
    __builtin_amdgcn_s_barrier();
    asm volatile("" ::: "memory");
  }

  // ---- peeled last tile ----
  {
    const char* pb = smem + ((NIT - 1) & 1) * 4096;
    bf16x8 pa0 = *(const bf16x8*)(pb + paoffA);
    bf16x8 pa1 = *(const bf16x8*)(pb + paoffB);
    bf16x8 vb0 = *(const bf16x8*)(vp[0]);
    bf16x8 vb1 = *(const bf16x8*)(vp[1]);
    bf16x8 vb2 = *(const bf16x8*)(vp[2]);
    bf16x8 vb3 = *(const bf16x8*)(vp[3]);
    acc[0][0] = __builtin_amdgcn_mfma_f32_16x16x32_bf16(pa0, vb0, acc[0][0], 0, 0, 0);
    acc[1][0] = __builtin_amdgcn_mfma_f32_16x16x32_bf16(pa1, vb0, acc[1][0], 0, 0, 0);
    acc[0][1] = __builtin_amdgcn_mfma_f32_16x16x32_bf16(pa0, vb1, acc[0][1], 0, 0, 0);
    acc[1][1] = __builtin_amdgcn_mfma_f32_16x16x32_bf16(pa1, vb1, acc[1][1], 0, 0, 0);
    acc[0][2] = __builtin_amdgcn_mfma_f32_16x16x32_bf16(pa0, vb2, acc[0][2], 0, 0, 0);
    acc[1][2] = __builtin_amdgcn_mfma_f32_16x16x32_bf16(pa1, vb2, acc[1][2], 0, 0, 0);
    acc[0][3] = __builtin_amdgcn_mfma_f32_16x16x32_bf16(pa0, vb3, acc[0][3], 0, 0, 0);
    acc[1][3] = __builtin_amdgcn_mfma_f32_16x16x32_bf16(pa1, vb3, acc[1][3], 0, 0, 0);
  }

#pragma unroll
  for (int at = 0; at < 2; ++at)
#pragma unroll
    for (int n = 0; n < 4; ++n)
#pragma unroll
      for (int r = 0; r < 4; ++r) {
        int h = hb + (w >> 2) * 32 + at * 16 + 4 * g + r;
        int e = eb + (w & 3) * 64 + n * 16 + row;
        out[(bH + h) * (size_t)EN + e] = acc[at][n][r];
      }
}

// ================= fallback path (round-1 kernels, ws < 40.5 MB) =================
__global__ __launch_bounds__(256) void k_stats_o(const float* __restrict__ xd,
                                                 const float* __restrict__ yd,
                                                 float* __restrict__ mz) {
  const int b = blockIdx.y;
  const int w = threadIdx.x >> 6;
  const int lane = threadIdx.x & 63;
  const int row = lane & 15, g = lane >> 4;
  const int lb = blockIdx.x * 64 + w * 16;
  const float* xp = xd + ((size_t)b * LN + lb + row) * KN + g * 8;
  bf16x8 a0 = cvt8s(xp, 1.0f), a1 = cvt8s(xp + 32, 1.0f);
  float m[4], s[4];
#pragma unroll
  for (int r = 0; r < 4; ++r) { m[r] = -1e30f; s[r] = 0.f; }
  const float* ybp = yd + ((size_t)b * HN + row) * KN + g * 8;
  for (int h0 = 0; h0 < HN; h0 += 16) {
    bf16x8 b0 = cvt8s(ybp + (size_t)h0 * KN, 1.0f);
    bf16x8 b1 = cvt8s(ybp + (size_t)h0 * KN + 32, 1.0f);
    f32x4 acc = {0.f, 0.f, 0.f, 0.f};
    acc = __builtin_amdgcn_mfma_f32_16x16x32_bf16(a0, b0, acc, 0, 0, 0);
    acc = __builtin_amdgcn_mfma_f32_16x16x32_bf16(a1, b1, acc, 0, 0, 0);
#pragma unroll
    for (int r = 0; r < 4; ++r) {
      float v = acc[r] * 0.125f;
      float mn = fmaxf(m[r], v);
      s[r] = s[r] * __expf(m[r] - mn) + __expf(v - mn);
      m[r] = mn;
    }
  }
#pragma unroll
  for (int d = 1; d < 16; d <<= 1) {
#pragma unroll
    for (int r = 0; r < 4; ++r) {
      float mo = __shfl_xor(m[r], d);
      float so = __shfl_xor(s[r], d);
      float mn = fmaxf(m[r], mo);
      s[r] = s[r] * __expf(m[r] - mn) + so * __expf(mo - mn);
      m[r] = mn;
    }
  }
  if (row == 0) {
#pragma unroll
    for (int r = 0; r < 4; ++r) {
      size_t idx = (size_t)b * LN + lb + 4 * g + r;
      mz[idx] = m[r];
      mz[(size_t)BN * LN + idx] = 1.0f / s[r];
    }
  }
}

__global__ __launch_bounds__(512) void k_main_o(const float* __restrict__ vals,
                                                const float* __restrict__ xd,
                                                const float* __restrict__ yd,
                                                const float* __restrict__ mz,
                                                float* __restrict__ out) {
  __shared__ short vT[256][34];
  __shared__ short pT[128][34];
  __shared__ short xT[32][72];
  __shared__ float smm[32], smz[32];
  const int b = blockIdx.z;
  const int hb = blockIdx.x * 128;
  const int eb = blockIdx.y * 256;
  const int tid = threadIdx.x;
  const int w = tid >> 6, lane = tid & 63;
  const int row = lane & 15, g = lane >> 4;
  const float* yp = yd + ((size_t)b * HN + hb + w * 16 + row) * KN + g * 8;
  bf16x8 ya0 = cvt8s(yp, 1.0f), ya1 = cvt8s(yp + 32, 1.0f);
  f32x4 acc[16];
#pragma unroll
  for (int n = 0; n < 16; ++n) acc[n] = (f32x4){0.f, 0.f, 0.f, 0.f};
  const float* mzb = mz + (size_t)b * LN;
  const float* rzb = mz + (size_t)BN * LN + (size_t)b * LN;
  for (int l0 = 0; l0 < LN; l0 += 32) {
    __syncthreads();
    {
      int xl = tid >> 4, xk = (tid & 15) * 4;
      f32x4 xv = *(const f32x4*)(xd + ((size_t)b * LN + l0 + xl) * KN + xk);
      union { short h[4]; int i[2]; } u;
      u.h[0] = f2b(xv[0]); u.h[1] = f2b(xv[1]); u.h[2] = f2b(xv[2]); u.h[3] = f2b(xv[3]);
      int* dst = (int*)(&xT[xl][xk]);
      dst[0] = u.i[0]; dst[1] = u.i[1];
    }
#pragma unroll
    for (int lp = 0; lp < 4; ++lp) {
      int vl = (tid >> 6) + lp * 8;
      const float* vrow = vals + ((size_t)b * LN + l0 + vl) * EN + eb;
#pragma unroll
      for (int u2 = 0; u2 < 4; ++u2) {
        int e = (tid & 63) + u2 * 64;
        vT[e][vl] = f2b(vrow[e]);
      }
    }
    if (tid < 32) { smm[tid] = mzb[l0 + tid]; smz[tid] = rzb[l0 + tid]; }
    __syncthreads();
#pragma unroll
    for (int t2 = 0; t2 < 2; ++t2) {
      const short* xr = &xT[t2 * 16 + row][0];
      bf16x8 xb0 = *(const bf16x8*)(xr + 8 * g);
      bf16x8 xb1 = *(const bf16x8*)(xr + 32 + 8 * g);
      f32x4 sa = {0.f, 0.f, 0.f, 0.f};
      sa = __builtin_amdgcn_mfma_f32_16x16x32_bf16(ya0, xb0, sa, 0, 0, 0);
      sa = __builtin_amdgcn_mfma_f32_16x16x32_bf16(ya1, xb1, sa, 0, 0, 0);
      int lcol = t2 * 16 + row;
      float mm = smm[lcol], zz = smz[lcol];
#pragma unroll
      for (int r = 0; r < 4; ++r) {
        float p2 = __expf(sa[r] * 0.125f - mm) * zz;
        pT[w * 16 + 4 * g + r][lcol] = f2b(p2);
      }
    }
    __syncthreads();
    bf16x8 pa;
    {
      const int* pi = (const int*)(&pT[w * 16 + row][0] + 8 * g);
      union { int i[4]; bf16x8 f; } u;
      u.i[0] = pi[0]; u.i[1] = pi[1]; u.i[2] = pi[2]; u.i[3] = pi[3];
      pa = u.f;
    }
#pragma unroll
    for (int n = 0; n < 16; ++n) {
      const int* vi = (const int*)(&vT[n * 16 + row][0] + 8 * g);
      union { int i[4]; bf16x8 f; } u;
      u.i[0] = vi[0]; u.i[1] = vi[1]; u.i[2] = vi[2]; u.i[3] = vi[3];
      acc[n] = __builtin_amdgcn_mfma_f32_16x16x32_bf16(pa, u.f, acc[n], 0, 0, 0);
    }
  }
#pragma unroll
  for (int n = 0; n < 16; ++n)
#pragma unroll
    for (int r = 0; r < 4; ++r) {
      int h = hb + w * 16 + 4 * g + r;
      int e = eb + n * 16 + row;
      out[((size_t)b * HN + h) * EN + e] = acc[n][r];
    }
}

extern "C" void kernel_launch(void* const* d_in, const int* in_sizes, int n_in,
                              void* d_out, int out_size, void* d_ws, size_t ws_size,
                              hipStream_t stream) {
  const float* vals = (const float*)d_in[2];
  const float* xd = (const float*)d_in[3];
  const float* yd = (const float*)d_in[4];
  float* out = (float*)d_out;

  if (ws_size >= 40501248ull) {
    char* wsb = (char*)d_ws;
    short* valsT = (short*)wsb;                       // 33554432 B
    short* xbuf  = (short*)(wsb + 33554432);          //  4194304 B
    short* ybuf  = (short*)(wsb + 37748736);          //  2097152 B
    float* ps    = (float*)(wsb + 39845888);          //   524288 B
    float* wv    = (float*)(wsb + 40370176);          //   131072 B

    k_prep<<<dim3(6656), 256, 0, stream>>>(vals, valsT, xd, xbuf, yd, ybuf, ps);
    k_comb<<<dim3(BN * LN / 256), 256, 0, stream>>>(ps, wv);
    k_main6<<<dim3(512), 512, 0, stream>>>(valsT, xbuf, ybuf, wv, out);
  } else {
    float* mz = (float*)d_ws;
    k_stats_o<<<dim3(LN / 64, BN), 256, 0, stream>>>(xd, yd, mz);
    k_main_o<<<dim3(HN / 128, EN / 256, BN), 512, 0, stream>>>(vals, xd, yd, mz, out);
  }
}

// Round 8
// 206.125 us; speedup vs baseline: 1.8802x; 1.8802x over previous
//
#include <hip/hip_runtime.h>
#include <hip/hip_bf16.h>

#define BN 8
#define LN 4096
#define HN 2048
#define EN 512
#define KN 64
#define LT 32
#define NIT 128

typedef __attribute__((ext_vector_type(8))) short bf16x8;
typedef __attribute__((ext_vector_type(4))) float f32x4;
typedef __attribute__((ext_vector_type(4))) unsigned u32x4;

__device__ __forceinline__ short f2b(float x) {
  union { float f; unsigned u; } v; v.f = x;
  unsigned r = v.u + 0x7fffu + ((v.u >> 16) & 1u);  // RNE f32->bf16
  return (short)(r >> 16);
}

__device__ __forceinline__ bf16x8 cvt8s(const float* __restrict__ p, float s) {
  f32x4 a = *(const f32x4*)(p);
  f32x4 b = *(const f32x4*)(p + 4);
  bf16x8 r;
  r[0] = f2b(a[0] * s); r[1] = f2b(a[1] * s); r[2] = f2b(a[2] * s); r[3] = f2b(a[3] * s);
  r[4] = f2b(b[0] * s); r[5] = f2b(b[1] * s); r[6] = f2b(b[2] * s); r[7] = f2b(b[3] * s);
  return r;
}

__device__ __forceinline__ void gload16(const void* g, void* s) {
  __builtin_amdgcn_global_load_lds(
      (const __attribute__((address_space(1))) unsigned int*)(unsigned long long)g,
      (__attribute__((address_space(3))) unsigned int*)(unsigned int)(unsigned long long)s,
      16, 0, 0);
}

// ---------- merged prep: cvt (0..1535) | prep_v (1536..5631) | stats raw (5632..6655) ----------
__global__ __launch_bounds__(256) void k_prep(const float* __restrict__ vals,
                                              short* __restrict__ valsT,
                                              const float* __restrict__ xd,
                                              short* __restrict__ xo,
                                              const float* __restrict__ yd,
                                              short* __restrict__ yo,
                                              float* __restrict__ ps) {
  __shared__ unsigned trT[2048];
  const int bx = blockIdx.x;
  const int tid = threadIdx.x;
  const float c0 = 0.125f * 1.4426950408889634f;  // scale * log2(e)
  if (bx < 1536) {
    const float* src;
    short* dst;
    float scale;
    int i;
    if (bx < 1024) { i = bx * 256 + tid; src = xd; dst = xo; scale = c0; }
    else           { i = (bx - 1024) * 256 + tid; src = yd; dst = yo; scale = 1.0f; }
    *(bf16x8*)(dst + (size_t)i * 8) = cvt8s(src + (size_t)i * 8, scale);
  } else if (bx < 5632) {
    // ---- prep_v: vals [b][l][e] f32 -> valsT [b][e][l] bf16 (64x64 tile) ----
    const int idx = bx - 1536;
    const int b = idx >> 9;
    const int e0 = ((idx >> 6) & 7) * 64;
    const int l0 = (idx & 63) * 64;
    {
      int lr2 = tid >> 3;
      int ec = (tid & 7) * 8;
      const float* r0 = vals + ((size_t)b * LN + l0 + 2 * lr2) * EN + e0 + ec;
      const float* r1 = r0 + EN;
      f32x4 a0 = *(const f32x4*)r0, a1 = *(const f32x4*)(r0 + 4);
      f32x4 cc0 = *(const f32x4*)r1, cc1 = *(const f32x4*)(r1 + 4);
#pragma unroll
      for (int j = 0; j < 8; ++j) {
        float lo = (j < 4) ? a0[j] : a1[j - 4];
        float hi = (j < 4) ? cc0[j] : cc1[j - 4];
        unsigned dw = (unsigned)(unsigned short)f2b(lo) |
                      ((unsigned)(unsigned short)f2b(hi) << 16);
        int e = ec + j;
        int sz = (((e >> 3) ^ e) & 7) << 2;
        trT[e * 32 + (lr2 ^ sz)] = dw;
      }
    }
    __syncthreads();
    {
      int er = tid >> 2, lq = (tid & 3) * 8;
      int sr = ((er >> 3) ^ er) & 7;
      const unsigned* base = trT + er * 32;
      u32x4 u0 = *(const u32x4*)(base + ((((lq >> 2) + 0) ^ sr) << 2));
      u32x4 u1 = *(const u32x4*)(base + ((((lq >> 2) + 1) ^ sr) << 2));
      short* dst = valsT + ((size_t)b * EN + e0 + er) * LN + l0 + 2 * lq;
      *(u32x4*)dst = u0;
      *(u32x4*)(dst + 8) = u1;
    }
  } else {
    // ---- stats: ps[hc][b][l] = sum over 512 h of 2^u ----
    const int idx = bx - 5632;
    const int b = (idx >> 5) & 7, hc = idx >> 8;
    const int w = tid >> 6, lane = tid & 63;
    const int row = lane & 15, g = lane >> 4;
    const int lb = (idx & 31) * 128 + w * 32;
    const size_t bL = (size_t)b * LN, bH = (size_t)b * HN;
    bf16x8 xa[2][2];
#pragma unroll
    for (int lt = 0; lt < 2; ++lt) {
      const float* xp = xd + (bL + lb + lt * 16 + row) * KN + g * 8;
      xa[lt][0] = cvt8s(xp, c0);
      xa[lt][1] = cvt8s(xp + 32, c0);
    }
    float s[2][4] = {{0.f, 0.f, 0.f, 0.f}, {0.f, 0.f, 0.f, 0.f}};
    const float* ybase = yd + (bH + hc * 512 + row) * KN + g * 8;
#pragma unroll 2
    for (int it = 0; it < 32; ++it) {
      const float* yp = ybase + (size_t)it * (16 * KN);
      bf16x8 y0 = cvt8s(yp, 1.0f);
      bf16x8 y1 = cvt8s(yp + 32, 1.0f);
#pragma unroll
      for (int lt = 0; lt < 2; ++lt) {
        f32x4 a = {0.f, 0.f, 0.f, 0.f};
        a = __builtin_amdgcn_mfma_f32_16x16x32_bf16(xa[lt][0], y0, a, 0, 0, 0);
        a = __builtin_amdgcn_mfma_f32_16x16x32_bf16(xa[lt][1], y1, a, 0, 0, 0);
#pragma unroll
        for (int r = 0; r < 4; ++r) s[lt][r] += __builtin_amdgcn_exp2f(a[r]);
      }
    }
#pragma unroll
    for (int d = 1; d < 16; d <<= 1)
#pragma unroll
      for (int lt = 0; lt < 2; ++lt)
#pragma unroll
        for (int r = 0; r < 4; ++r) s[lt][r] += __shfl_xor(s[lt][r], d);
    if (row == 0) {
#pragma unroll
      for (int lt = 0; lt < 2; ++lt)
#pragma unroll
        for (int r = 0; r < 4; ++r)
          ps[(size_t)hc * (BN * LN) + bL + lb + lt * 16 + 4 * g + r] = s[lt][r];
    }
  }
}

__global__ void k_comb(const float* __restrict__ ps, float* __restrict__ wv) {
  int idx = blockIdx.x * 256 + threadIdx.x;
  float z = ps[idx] + ps[BN * LN + idx] + ps[2 * BN * LN + idx] + ps[3 * BN * LN + idx];
  wv[idx] = 1.0f / z;
}

// ---------- main v7: 4 waves x 64x64 tiles (8B LDS/MFMA), v4 pipeline ----------
// LDS: vT[3]x16384 @0 | xT[3]x4096 @49152 | pT[2]x4096 @61440 | sw[3]x128 @69632
__global__ __launch_bounds__(256, 2) void k_main7(
    const short* __restrict__ valsT, const short* __restrict__ xb,
    const short* __restrict__ yb, const float* __restrict__ wv,
    float* __restrict__ out) {
  __shared__ __align__(16) char smem[70016];
  const int tid = threadIdx.x;
  const int w = tid >> 6, lane = tid & 63;
  const int row = lane & 15, g = lane >> 4;

  const int f = blockIdx.x;
  const int b = f & 7;                 // XCD f%8 <- batch b (valsT[b] 4MB per XCD L2)
  const int rest = f >> 3;             // 0..63
  const int hb = (rest & 31) * 64;
  const int eb = (rest >> 5) * 256;
  const size_t bL = (size_t)b * LN, bH = (size_t)b * HN;
  const int wbase = __builtin_amdgcn_readfirstlane(tid & ~63);  // w*64

  // ---- staging source pointers ----
  const short* vsrc[4];
#pragma unroll
  for (int j = 0; j < 4; ++j) {
    int i = j * 256 + tid;
    int e = i >> 2, sl = (i & 3) ^ ((e >> 1) & 3);
    vsrc[j] = valsT + (((size_t)b * EN + eb + e) << 12) + 8 * sl;
  }
  const short* xsrc = xb + ((bL + (tid >> 3)) << 6) + 8 * ((tid & 7) ^ ((tid >> 3) & 7));
  const float* ssrc = wv + bL + 4 * tid;  // tid<8

  // issue order per iter: xT(1), sw(1 w0), vT(4) -> vmcnt(4) leaves newest vT quad
  auto stage = [&](int t) {
    int m3 = t % 3;
    gload16(xsrc + ((size_t)t << 11), smem + 49152 + m3 * 4096 + wbase * 16);
    if (tid < 8)
      gload16(ssrc + t * 32, smem + 69632 + m3 * 128);
#pragma unroll
    for (int j = 0; j < 4; ++j)
      gload16(vsrc[j] + t * 32, smem + m3 * 16384 + j * 4096 + wbase * 16);
  };

  // ---- produce role: wave w -> h-tile w, both l-halves ----
  bf16x8 ya0, ya1;
  {
    const short* yp = yb + ((bH + hb + w * 16 + row) << 6) + 8 * g;
    ya0 = *(const bf16x8*)yp;
    ya1 = *(const bf16x8*)(yp + 32);
  }
  int xoffA[2], xoffB[2], poff[2], swoff[2];
#pragma unroll
  for (int lt = 0; lt < 2; ++lt) {
    int lr = lt * 16 + row;
    int sp0 = g ^ (lr & 7);
    xoffA[lt] = (lr << 7) + (sp0 << 4);
    xoffB[lt] = (lr << 7) + ((sp0 ^ 4) << 4);
    int hq1 = w * 16 + row;
    poff[lt] = hq1 * 64 + (((2 * lt + (g >> 1)) ^ ((hq1 >> 1) & 3)) << 4) + (g & 1) * 8;
    swoff[lt] = lt * 16 + 4 * g;
  }

  // ---- consume role: wave w = e-quarter, all 64 h ----
  int paoff[4], vboff[4];
#pragma unroll
  for (int at = 0; at < 4; ++at) {
    int hq = at * 16 + row;
    paoff[at] = hq * 64 + ((g ^ ((hq >> 1) & 3)) << 4);
  }
#pragma unroll
  for (int n = 0; n < 4; ++n) {
    int el = w * 64 + n * 16 + row;
    vboff[n] = el * 64 + ((g ^ ((el >> 1) & 3)) << 4);
  }

  f32x4 acc[4][4];
#pragma unroll
  for (int at = 0; at < 4; ++at)
#pragma unroll
    for (int n = 0; n < 4; ++n) acc[at][n] = (f32x4){0.f, 0.f, 0.f, 0.f};

  auto produce = [&](int t) {
    const char* xbuf = smem + 49152 + (t % 3) * 4096;
    const float* swp = (const float*)(smem + 69632 + (t % 3) * 128);
    char* pdst = smem + 61440 + (t & 1) * 4096;
#pragma unroll
    for (int lt = 0; lt < 2; ++lt) {
      bf16x8 xa0 = *(const bf16x8*)(xbuf + xoffA[lt]);
      bf16x8 xa1 = *(const bf16x8*)(xbuf + xoffB[lt]);
      f32x4 sws = *(const f32x4*)(swp + swoff[lt]);
      f32x4 s4 = {0.f, 0.f, 0.f, 0.f};
      s4 = __builtin_amdgcn_mfma_f32_16x16x32_bf16(xa0, ya0, s4, 0, 0, 0);
      s4 = __builtin_amdgcn_mfma_f32_16x16x32_bf16(xa1, ya1, s4, 0, 0, 0);
      unsigned u0 = (unsigned)(unsigned short)f2b(__builtin_amdgcn_exp2f(s4[0]) * sws[0]) |
                    ((unsigned)(unsigned short)f2b(__builtin_amdgcn_exp2f(s4[1]) * sws[1]) << 16);
      unsigned u1 = (unsigned)(unsigned short)f2b(__builtin_amdgcn_exp2f(s4[2]) * sws[2]) |
                    ((unsigned)(unsigned short)f2b(__builtin_amdgcn_exp2f(s4[3]) * sws[3]) << 16);
      *(unsigned long long*)(pdst + poff[lt]) =
          (unsigned long long)u0 | ((unsigned long long)u1 << 32);
    }
  };

  auto consume = [&](int t) {
    const char* vbuf = smem + (t % 3) * 16384;
    const char* pbuf = smem + 61440 + (t & 1) * 4096;
    bf16x8 pa0 = *(const bf16x8*)(pbuf + paoff[0]);
    bf16x8 pa1 = *(const bf16x8*)(pbuf + paoff[1]);
    bf16x8 pa2 = *(const bf16x8*)(pbuf + paoff[2]);
    bf16x8 pa3 = *(const bf16x8*)(pbuf + paoff[3]);
    bf16x8 vb0 = *(const bf16x8*)(vbuf + vboff[0]);
    bf16x8 vb1 = *(const bf16x8*)(vbuf + vboff[1]);
    bf16x8 vb2 = *(const bf16x8*)(vbuf + vboff[2]);
    bf16x8 vb3 = *(const bf16x8*)(vbuf + vboff[3]);
    __builtin_amdgcn_s_setprio(1);
    acc[0][0] = __builtin_amdgcn_mfma_f32_16x16x32_bf16(pa0, vb0, acc[0][0], 0, 0, 0);
    acc[1][0] = __builtin_amdgcn_mfma_f32_16x16x32_bf16(pa1, vb0, acc[1][0], 0, 0, 0);
    acc[2][0] = __builtin_amdgcn_mfma_f32_16x16x32_bf16(pa2, vb0, acc[2][0], 0, 0, 0);
    acc[3][0] = __builtin_amdgcn_mfma_f32_16x16x32_bf16(pa3, vb0, acc[3][0], 0, 0, 0);
    acc[0][1] = __builtin_amdgcn_mfma_f32_16x16x32_bf16(pa0, vb1, acc[0][1], 0, 0, 0);
    acc[1][1] = __builtin_amdgcn_mfma_f32_16x16x32_bf16(pa1, vb1, acc[1][1], 0, 0, 0);
    acc[2][1] = __builtin_amdgcn_mfma_f32_16x16x32_bf16(pa2, vb1, acc[2][1], 0, 0, 0);
    acc[3][1] = __builtin_amdgcn_mfma_f32_16x16x32_bf16(pa3, vb1, acc[3][1], 0, 0, 0);
    acc[0][2] = __builtin_amdgcn_mfma_f32_16x16x32_bf16(pa0, vb2, acc[0][2], 0, 0, 0);
    acc[1][2] = __builtin_amdgcn_mfma_f32_16x16x32_bf16(pa1, vb2, acc[1][2], 0, 0, 0);
    acc[2][2] = __builtin_amdgcn_mfma_f32_16x16x32_bf16(pa2, vb2, acc[2][2], 0, 0, 0);
    acc[3][2] = __builtin_amdgcn_mfma_f32_16x16x32_bf16(pa3, vb2, acc[3][2], 0, 0, 0);
    acc[0][3] = __builtin_amdgcn_mfma_f32_16x16x32_bf16(pa0, vb3, acc[0][3], 0, 0, 0);
    acc[1][3] = __builtin_amdgcn_mfma_f32_16x16x32_bf16(pa1, vb3, acc[1][3], 0, 0, 0);
    acc[2][3] = __builtin_amdgcn_mfma_f32_16x16x32_bf16(pa2, vb3, acc[2][3], 0, 0, 0);
    acc[3][3] = __builtin_amdgcn_mfma_f32_16x16x32_bf16(pa3, vb3, acc[3][3], 0, 0, 0);
    __builtin_amdgcn_s_setprio(0);
  };

  // ---- prologue: stage 0,1; drain all but vT(1) quad; produce(0) ----
  stage(0);
  stage(1);
  asm volatile("s_waitcnt vmcnt(4)" ::: "memory");
  __builtin_amdgcn_s_barrier();
  asm volatile("" ::: "memory");
  produce(0);
  asm volatile("s_waitcnt lgkmcnt(0)" ::: "memory");
  __builtin_amdgcn_s_barrier();
  asm volatile("" ::: "memory");

  for (int it = 0; it < NIT; ++it) {
    if (it + 2 < NIT) stage(it + 2);
    if (it + 1 < NIT) produce(it + 1);
    consume(it);
    if (it + 1 < NIT) {
      if (it + 2 < NIT)
        asm volatile("s_waitcnt vmcnt(4) lgkmcnt(0)" ::: "memory");
      else
        asm volatile("s_waitcnt vmcnt(0) lgkmcnt(0)" ::: "memory");
      __builtin_amdgcn_s_barrier();
      asm volatile("" ::: "memory");
    }
  }

#pragma unroll
  for (int at = 0; at < 4; ++at)
#pragma unroll
    for (int n = 0; n < 4; ++n)
#pragma unroll
      for (int r = 0; r < 4; ++r) {
        int h = hb + at * 16 + 4 * g + r;
        int e = eb + w * 64 + n * 16 + row;
        out[(bH + h) * (size_t)EN + e] = acc[at][n][r];
      }
}

// ================= fallback path (round-1 kernels, ws < 40.5 MB) =================
__global__ __launch_bounds__(256) void k_stats_o(const float* __restrict__ xd,
                                                 const float* __restrict__ yd,
                                                 float* __restrict__ mz) {
  const int b = blockIdx.y;
  const int w = threadIdx.x >> 6;
  const int lane = threadIdx.x & 63;
  const int row = lane & 15, g = lane >> 4;
  const int lb = blockIdx.x * 64 + w * 16;
  const float* xp = xd + ((size_t)b * LN + lb + row) * KN + g * 8;
  bf16x8 a0 = cvt8s(xp, 1.0f), a1 = cvt8s(xp + 32, 1.0f);
  float m[4], s[4];
#pragma unroll
  for (int r = 0; r < 4; ++r) { m[r] = -1e30f; s[r] = 0.f; }
  const float* ybp = yd + ((size_t)b * HN + row) * KN + g * 8;
  for (int h0 = 0; h0 < HN; h0 += 16) {
    bf16x8 b0 = cvt8s(ybp + (size_t)h0 * KN, 1.0f);
    bf16x8 b1 = cvt8s(ybp + (size_t)h0 * KN + 32, 1.0f);
    f32x4 acc = {0.f, 0.f, 0.f, 0.f};
    acc = __builtin_amdgcn_mfma_f32_16x16x32_bf16(a0, b0, acc, 0, 0, 0);
    acc = __builtin_amdgcn_mfma_f32_16x16x32_bf16(a1, b1, acc, 0, 0, 0);
#pragma unroll
    for (int r = 0; r < 4; ++r) {
      float v = acc[r] * 0.125f;
      float mn = fmaxf(m[r], v);
      s[r] = s[r] * __expf(m[r] - mn) + __expf(v - mn);
      m[r] = mn;
    }
  }
#pragma unroll
  for (int d = 1; d < 16; d <<= 1) {
#pragma unroll
    for (int r = 0; r < 4; ++r) {
      float mo = __shfl_xor(m[r], d);
      float so = __shfl_xor(s[r], d);
      float mn = fmaxf(m[r], mo);
      s[r] = s[r] * __expf(m[r] - mn) + so * __expf(mo - mn);
      m[r] = mn;
    }
  }
  if (row == 0) {
#pragma unroll
    for (int r = 0; r < 4; ++r) {
      size_t idx = (size_t)b * LN + lb + 4 * g + r;
      mz[idx] = m[r];
      mz[(size_t)BN * LN + idx] = 1.0f / s[r];
    }
  }
}

__global__ __launch_bounds__(512) void k_main_o(const float* __restrict__ vals,
                                                const float* __restrict__ xd,
                                                const float* __restrict__ yd,
                                                const float* __restrict__ mz,
                                                float* __restrict__ out) {
  __shared__ short vT[256][34];
  __shared__ short pT[128][34];
  __shared__ short xT[32][72];
  __shared__ float smm[32], smz[32];
  const int b = blockIdx.z;
  const int hb = blockIdx.x * 128;
  const int eb = blockIdx.y * 256;
  const int tid = threadIdx.x;
  const int w = tid >> 6, lane = tid & 63;
  const int row = lane & 15, g = lane >> 4;
  const float* yp = yd + ((size_t)b * HN + hb + w * 16 + row) * KN + g * 8;
  bf16x8 ya0 = cvt8s(yp, 1.0f), ya1 = cvt8s(yp + 32, 1.0f);
  f32x4 acc[16];
#pragma unroll
  for (int n = 0; n < 16; ++n) acc[n] = (f32x4){0.f, 0.f, 0.f, 0.f};
  const float* mzb = mz + (size_t)b * LN;
  const float* rzb = mz + (size_t)BN * LN + (size_t)b * LN;
  for (int l0 = 0; l0 < LN; l0 += 32) {
    __syncthreads();
    {
      int xl = tid >> 4, xk = (tid & 15) * 4;
      f32x4 xv = *(const f32x4*)(xd + ((size_t)b * LN + l0 + xl) * KN + xk);
      union { short h[4]; int i[2]; } u;
      u.h[0] = f2b(xv[0]); u.h[1] = f2b(xv[1]); u.h[2] = f2b(xv[2]); u.h[3] = f2b(xv[3]);
      int* dst = (int*)(&xT[xl][xk]);
      dst[0] = u.i[0]; dst[1] = u.i[1];
    }
#pragma unroll
    for (int lp = 0; lp < 4; ++lp) {
      int vl = (tid >> 6) + lp * 8;
      const float* vrow = vals + ((size_t)b * LN + l0 + vl) * EN + eb;
#pragma unroll
      for (int u2 = 0; u2 < 4; ++u2) {
        int e = (tid & 63) + u2 * 64;
        vT[e][vl] = f2b(vrow[e]);
      }
    }
    if (tid < 32) { smm[tid] = mzb[l0 + tid]; smz[tid] = rzb[l0 + tid]; }
    __syncthreads();
#pragma unroll
    for (int t2 = 0; t2 < 2; ++t2) {
      const short* xr = &xT[t2 * 16 + row][0];
      bf16x8 xb0 = *(const bf16x8*)(xr + 8 * g);
      bf16x8 xb1 = *(const bf16x8*)(xr + 32 + 8 * g);
      f32x4 sa = {0.f, 0.f, 0.f, 0.f};
      sa = __builtin_amdgcn_mfma_f32_16x16x32_bf16(ya0, xb0, sa, 0, 0, 0);
      sa = __builtin_amdgcn_mfma_f32_16x16x32_bf16(ya1, xb1, sa, 0, 0, 0);
      int lcol = t2 * 16 + row;
      float mm = smm[lcol], zz = smz[lcol];
#pragma unroll
      for (int r = 0; r < 4; ++r) {
        float p2 = __expf(sa[r] * 0.125f - mm) * zz;
        pT[w * 16 + 4 * g + r][lcol] = f2b(p2);
      }
    }
    __syncthreads();
    bf16x8 pa;
    {
      const int* pi = (const int*)(&pT[w * 16 + row][0] + 8 * g);
      union { int i[4]; bf16x8 f; } u;
      u.i[0] = pi[0]; u.i[1] = pi[1]; u.i[2] = pi[2]; u.i[3] = pi[3];
      pa = u.f;
    }
#pragma unroll
    for (int n = 0; n < 16; ++n) {
      const int* vi = (const int*)(&vT[n * 16 + row][0] + 8 * g);
      union { int i[4]; bf16x8 f; } u;
      u.i[0] = vi[0]; u.i[1] = vi[1]; u.i[2] = vi[2]; u.i[3] = vi[3];
      acc[n] = __builtin_amdgcn_mfma_f32_16x16x32_bf16(pa, u.f, acc[n], 0, 0, 0);
    }
  }
#pragma unroll
  for (int n = 0; n < 16; ++n)
#pragma unroll
    for (int r = 0; r < 4; ++r) {
      int h = hb + w * 16 + 4 * g + r;
      int e = eb + n * 16 + row;
      out[((size_t)b * HN + h) * EN + e] = acc[n][r];
    }
}

extern "C" void kernel_launch(void* const* d_in, const int* in_sizes, int n_in,
                              void* d_out, int out_size, void* d_ws, size_t ws_size,
                              hipStream_t stream) {
  const float* vals = (const float*)d_in[2];
  const float* xd = (const float*)d_in[3];
  const float* yd = (const float*)d_in[4];
  float* out = (float*)d_out;

  if (ws_size >= 40501248ull) {
    char* wsb = (char*)d_ws;
    short* valsT = (short*)wsb;                       // 33554432 B
    short* xbuf  = (short*)(wsb + 33554432);          //  4194304 B
    short* ybuf  = (short*)(wsb + 37748736);          //  2097152 B
    float* ps    = (float*)(wsb + 39845888);          //   524288 B
    float* wv    = (float*)(wsb + 40370176);          //   131072 B

    k_prep<<<dim3(6656), 256, 0, stream>>>(vals, valsT, xd, xbuf, yd, ybuf, ps);
    k_comb<<<dim3(BN * LN / 256), 256, 0, stream>>>(ps, wv);
    k_main7<<<dim3(512), 256, 0, stream>>>(valsT, xbuf, ybuf, wv, out);
  } else {
    float* mz = (float*)d_ws;
    k_stats_o<<<dim3(LN / 64, BN), 256, 0, stream>>>(xd, yd, mz);
    k_main_o<<<dim3(HN / 128, EN / 256, BN), 512, 0, stream>>>(vals, xd, yd, mz, out);
  }
}